// Round 12
// baseline (556.344 us; speedup 1.0000x reference)
//
#include <hip/hip_runtime.h>
#include <stdint.h>

#define N_NODES 100000
#define N_EDGES 1600000
#define F 128
#define NPBK 16                   // nodes per bucket
#define NBK (N_NODES / NPBK)      // 6250 buckets (exact)
#define NCB (8 * NBK)             // 50000 (copy,bucket) slices

typedef _Float16 f16;
typedef _Float16 f16x4 __attribute__((ext_vector_type(4)));
typedef _Float16 f16x8 __attribute__((ext_vector_type(8)));
typedef float f32x4 __attribute__((ext_vector_type(4)));

// edge pack: (src << 15) | (fp16 bits of w, sign bit dropped — w in [0,1))
__device__ inline float unpackw(unsigned int p) {
    unsigned short b = (unsigned short)(p & 0x7FFF);
    return (float)__builtin_bit_cast(f16, b);
}

// ---------------- XCD-privatized count histogram (copy = blockIdx & 7) ----------------
// Measured R9/R11: cross-XCD scattered/shared-line writes cost one 64B migration
// each. R12: stage is COPY-MAJOR so each XCD's write region is contiguous —
// no cross-XCD shared lines except 7 region boundaries.

__global__ void k_zero(uint4* p, int n16) {
    int i = blockIdx.x * blockDim.x + threadIdx.x;
    if (i < n16) p[i] = make_uint4(0, 0, 0, 0);
}

__global__ void k_hist8c(const int* __restrict__ ei, int* __restrict__ cnt8, int e) {
    int i = blockIdx.x * blockDim.x + threadIdx.x;
    if (i < e) {
        int d = ei[N_EDGES + i];
        int c = blockIdx.x & 7;
        atomicAdd(&cnt8[(size_t)c * N_NODES + d], 1);
    }
}

__global__ void k_reduce(const int* __restrict__ cnt8, int* __restrict__ cnt, int n) {
    int i = blockIdx.x * blockDim.x + threadIdx.x;
    if (i < n) {
        int c = 0;
#pragma unroll
        for (int k = 0; k < 8; k++) c += cnt8[(size_t)k * N_NODES + i];
        cnt[i] = c;
    }
}

// per-(copy,bucket) counts, flattened copy-major: bc[c*NBK + b]
__global__ void k_bcnt(const int* __restrict__ cnt8, int* __restrict__ bc) {
    int i = blockIdx.x * blockDim.x + threadIdx.x;
    if (i < NCB) {
        int c = i / NBK, b = i - c * NBK;
        int base = c * N_NODES + b * NPBK;
        int s = 0;
#pragma unroll
        for (int j = 0; j < NPBK; j++) s += cnt8[base + j];
        bc[i] = s;
    }
}

// ---------------- hierarchical exclusive scan (shared by node & bucket scans) ----------------
__launch_bounds__(256)
__global__ void k_bsum(const int* __restrict__ cnt, int* __restrict__ bsum, int n) {
    int b = blockIdx.x, tid = threadIdx.x;
    int base = b * 1024 + tid * 4;
    int s = 0;
#pragma unroll
    for (int j = 0; j < 4; j++)
        if (base + j < n) s += cnt[base + j];
    for (int off = 32; off; off >>= 1) s += __shfl_down(s, off, 64);
    __shared__ int ws[4];
    if ((tid & 63) == 0) ws[tid >> 6] = s;
    __syncthreads();
    if (tid == 0) bsum[b] = ws[0] + ws[1] + ws[2] + ws[3];
}

__launch_bounds__(128)
__global__ void k_bscan(int* bsum, int nb, int* total_out) {
    __shared__ int ls[128];
    int tid = threadIdx.x;
    int v = (tid < nb) ? bsum[tid] : 0;
    ls[tid] = v;
    __syncthreads();
    for (int off = 1; off < 128; off <<= 1) {
        int t = (tid >= off) ? ls[tid - off] : 0;
        __syncthreads();
        ls[tid] += t;
        __syncthreads();
    }
    int ex = tid ? ls[tid - 1] : 0;
    if (tid < nb) bsum[tid] = ex;
    if (tid == 0) *total_out = N_EDGES;
}

// node scan: writes row only
__launch_bounds__(256)
__global__ void k_scan2(int* __restrict__ cnt_pos, const int* __restrict__ boff,
                        int* __restrict__ row, int n) {
    __shared__ int ls[256];
    int b = blockIdx.x, tid = threadIdx.x;
    int base = b * 1024 + tid * 4;
    int v[4];
    int s = 0;
#pragma unroll
    for (int j = 0; j < 4; j++) {
        v[j] = (base + j < n) ? cnt_pos[base + j] : 0;
        s += v[j];
    }
    ls[tid] = s;
    __syncthreads();
    for (int off = 1; off < 256; off <<= 1) {
        int t = (tid >= off) ? ls[tid - off] : 0;
        __syncthreads();
        ls[tid] += t;
        __syncthreads();
    }
    int run = boff[b] + (tid ? ls[tid - 1] : 0);
#pragma unroll
    for (int j = 0; j < 4; j++) {
        int node = base + j;
        if (node < n) {
            row[node] = run;
            run += v[j];
        }
    }
}

// bucket scan: writes sbeg[] AND turns bc[] into the placeA cursor (prefix)
__launch_bounds__(256)
__global__ void k_scan2c(int* __restrict__ bc, const int* __restrict__ boff,
                         int* __restrict__ sbeg, int n) {
    __shared__ int ls[256];
    int b = blockIdx.x, tid = threadIdx.x;
    int base = b * 1024 + tid * 4;
    int v[4];
    int s = 0;
#pragma unroll
    for (int j = 0; j < 4; j++) {
        v[j] = (base + j < n) ? bc[base + j] : 0;
        s += v[j];
    }
    ls[tid] = s;
    __syncthreads();
    for (int off = 1; off < 256; off <<= 1) {
        int t = (tid >= off) ? ls[tid - off] : 0;
        __syncthreads();
        ls[tid] += t;
        __syncthreads();
    }
    int run = boff[b] + (tid ? ls[tid - 1] : 0);
#pragma unroll
    for (int j = 0; j < 4; j++) {
        int idx = base + j;
        if (idx < n) {
            sbeg[idx] = run;
            bc[idx] = run;   // cursor for placeA
            run += v[j];
        }
    }
}

// phase A: append into copy-major stage region (XCD-contiguous, migration-free)
__global__ void k_placeA(const int* __restrict__ ei, const float* __restrict__ w,
                         int* __restrict__ bc, int2* __restrict__ stage, int e) {
    int i = blockIdx.x * blockDim.x + threadIdx.x;
    if (i < e) {
        int s = ei[i];
        int d = ei[N_EDGES + i];
        int c = blockIdx.x & 7;
        int idx = c * NBK + (d >> 4);
        int local = d & (NPBK - 1);
        int p = atomicAdd(&bc[idx], 1);
        stage[p] = make_int2((local << 17) | s, __float_as_int(w[i]));
    }
}

// phase B: one wave per bucket; reads its 8 per-copy slices, dense final window
__launch_bounds__(256)
__global__ void k_placeB(const int2* __restrict__ stage, const int* __restrict__ row,
                         const int* __restrict__ sbeg, unsigned int* __restrict__ edges) {
    __shared__ int cur[4 * NPBK];
    int wave = threadIdx.x >> 6;
    int lane = threadIdx.x & 63;
    int b = blockIdx.x * 4 + wave;
    if (b >= NBK) return;
    int n0 = b * NPBK;
    if (lane < NPBK) cur[wave * NPBK + lane] = row[n0 + lane];
    __syncthreads();
#pragma unroll
    for (int c = 0; c < 8; c++) {
        int lo = sbeg[c * NBK + b];
        int hi = sbeg[c * NBK + b + 1];   // contiguous in scan order (sentinel at NCB)
        for (int j = lo + lane; j < hi; j += 64) {
            int2 rec = stage[j];
            int l = rec.x >> 17;
            int src = rec.x & 0x1FFFF;
            f16 hw = (f16)__int_as_float(rec.y);
            unsigned short wb = __builtin_bit_cast(unsigned short, hw);
            int p = atomicAdd(&cur[wave * NPBK + l], 1);
            edges[p] = ((unsigned int)src << 15) | (wb & 0x7FFF);
        }
    }
}

// deg from CSR (sequential stream, no atomics): deg = 1 + sum w
__global__ void k_deg(const unsigned int* __restrict__ edges, const int* __restrict__ row,
                      float* __restrict__ dinv, int n) {
    int i = blockIdx.x * blockDim.x + threadIdx.x;
    if (i >= n) return;
    float s = 1.0f;
    int beg = row[i], end = row[i + 1];
    for (int j = beg; j < end; j++) s += unpackw(edges[j]);
    dinv[i] = rsqrtf(s);
}

// ---------------- fp32 -> fp16 conversions ----------------

__global__ void k_cvt(const float* __restrict__ X, f16* __restrict__ Y, int n8) {
    int i = blockIdx.x * blockDim.x + threadIdx.x;
    if (i < n8) {
        float4 a = ((const float4*)X)[i * 2];
        float4 b = ((const float4*)X)[i * 2 + 1];
        f16x8 o;
        o[0] = (f16)a.x; o[1] = (f16)a.y; o[2] = (f16)a.z; o[3] = (f16)a.w;
        o[4] = (f16)b.x; o[5] = (f16)b.y; o[6] = (f16)b.z; o[7] = (f16)b.w;
        ((f16x8*)Y)[i] = o;
    }
}

__global__ void k_wt(const float* __restrict__ W, f16* __restrict__ Wt) {
    int t = threadIdx.x;
#pragma unroll
    for (int it = 0; it < 64; it++) {
        int idx = t + it * 256;
        int k = idx >> 7, n = idx & 127;
        Wt[n * 128 + k] = (f16)W[idx];
    }
}

// ---------------- fp16 MFMA GEMM, epilogue scales rows by dinv ----------------

#define LDK 136

__launch_bounds__(256, 2)
__global__ void k_gemm16(const f16* __restrict__ A, const f16* __restrict__ Wt,
                         const float* __restrict__ dinv, f16* __restrict__ H, int nrows) {
    __shared__ f16 Ws[128 * LDK];
    int tid = threadIdx.x;
    int r0 = blockIdx.x * 128;
    int wave = tid >> 6;
    int lane = tid & 63;
    int lrow = lane & 15;
    int quad = lane >> 4;

    f16x8 a[2][4];
#pragma unroll
    for (int mt = 0; mt < 2; mt++) {
        int row = r0 + wave * 32 + mt * 16 + lrow;
#pragma unroll
        for (int kc = 0; kc < 4; kc++) {
            if (row < nrows)
                a[mt][kc] = *(const f16x8*)&A[(size_t)row * F + kc * 32 + quad * 8];
            else
                a[mt][kc] = (f16x8){};
        }
    }
#pragma unroll
    for (int it = 0; it < 8; it++) {
        int c = tid + it * 256;
        int rw = c >> 4;
        int off = (c & 15) * 8;
        *(f16x8*)&Ws[rw * LDK + off] = *(const f16x8*)&Wt[rw * 128 + off];
    }
    __syncthreads();

    f32x4 acc[2][8] = {};
#pragma unroll
    for (int kc = 0; kc < 4; kc++) {
        f16x8 b[8];
#pragma unroll
        for (int nt = 0; nt < 8; nt++)
            b[nt] = *(const f16x8*)&Ws[(nt * 16 + lrow) * LDK + kc * 32 + quad * 8];
#pragma unroll
        for (int nt = 0; nt < 8; nt++) {
            acc[0][nt] = __builtin_amdgcn_mfma_f32_16x16x32_f16(a[0][kc], b[nt], acc[0][nt], 0, 0, 0);
            acc[1][nt] = __builtin_amdgcn_mfma_f32_16x16x32_f16(a[1][kc], b[nt], acc[1][nt], 0, 0, 0);
        }
    }
    __syncthreads();
#pragma unroll
    for (int mt = 0; mt < 2; mt++) {
#pragma unroll
        for (int r = 0; r < 4; r++) {
            int lr = wave * 32 + mt * 16 + quad * 4 + r;
            int grow = r0 + lr;
            float dv = (grow < nrows) ? dinv[grow] : 0.f;
#pragma unroll
            for (int nt = 0; nt < 8; nt++)
                Ws[lr * 132 + nt * 16 + lrow] = (f16)(acc[mt][nt][r] * dv);
        }
    }
    __syncthreads();
#pragma unroll
    for (int it = 0; it < 8; it++) {
        int c = it * 256 + tid;
        int rw = c >> 4;
        int col = (c & 15) * 8;
        int grow = r0 + rw;
        if (grow < nrows)
            *(f16x8*)&H[(size_t)grow * F + col] = *(const f16x8*)&Ws[rw * 132 + col];
    }
}

// ---------------- aggregation: quarter-wave 16B gathers, no per-edge dinv ----------------

__launch_bounds__(256)
__global__ void k_agg(const f16* __restrict__ H16, const int* __restrict__ row,
                      const unsigned int* __restrict__ edges,
                      const float* __restrict__ dinv, const float* __restrict__ bias,
                      f16* __restrict__ out, int n) {
    int node = blockIdx.x * 4 + (threadIdx.x >> 6);
    if (node >= n) return;
    int lane = threadIdx.x & 63;
    int qq = lane >> 4;
    int sub = lane & 15;
    float acc[8] = {0.f, 0.f, 0.f, 0.f, 0.f, 0.f, 0.f, 0.f};
    float acc2[8] = {0.f, 0.f, 0.f, 0.f, 0.f, 0.f, 0.f, 0.f};
    int beg = row[node], end = row[node + 1];
    int deg = end - beg;
    int t = qq;
    for (; t + 4 < deg; t += 8) {
        unsigned int e0 = edges[beg + t];
        unsigned int e1 = edges[beg + t + 4];
        float w0 = unpackw(e0);
        float w1 = unpackw(e1);
        f16x8 v0 = *(const f16x8*)&H16[(size_t)(e0 >> 15) * F + sub * 8];
        f16x8 v1 = *(const f16x8*)&H16[(size_t)(e1 >> 15) * F + sub * 8];
#pragma unroll
        for (int j = 0; j < 8; j++) {
            acc[j] = fmaf(w0, (float)v0[j], acc[j]);
            acc2[j] = fmaf(w1, (float)v1[j], acc2[j]);
        }
    }
    for (; t < deg; t += 4) {
        unsigned int e0 = edges[beg + t];
        float w0 = unpackw(e0);
        f16x8 v0 = *(const f16x8*)&H16[(size_t)(e0 >> 15) * F + sub * 8];
#pragma unroll
        for (int j = 0; j < 8; j++)
            acc[j] = fmaf(w0, (float)v0[j], acc[j]);
    }
#pragma unroll
    for (int j = 0; j < 8; j++) {
        acc[j] += acc2[j];
        acc[j] += __shfl_xor(acc[j], 16, 64);
        acc[j] += __shfl_xor(acc[j], 32, 64);
    }
    if (lane < 16) {
        float dd = dinv[node];
        f16x8 h = *(const f16x8*)&H16[(size_t)node * F + lane * 8];
        float4 b0 = *(const float4*)&bias[lane * 8];
        float4 b1 = *(const float4*)&bias[lane * 8 + 4];
        float bb[8] = {b0.x, b0.y, b0.z, b0.w, b1.x, b1.y, b1.z, b1.w};
        f16x8 o;
#pragma unroll
        for (int j = 0; j < 8; j++) {
            float r = fmaxf(fmaf(dd, acc[j] + (float)h[j], bb[j]), 0.f);
            o[j] = (f16)r;
        }
        *(f16x8*)&out[(size_t)node * F + lane * 8] = o;
    }
}

// agg3 fused with final dot: s'[node] = dinv[node] * ( relu(agg3) . Wfin )
__launch_bounds__(256)
__global__ void k_agg_dot(const f16* __restrict__ H16, const int* __restrict__ row,
                          const unsigned int* __restrict__ edges,
                          const float* __restrict__ dinv, const float* __restrict__ bias,
                          const float* __restrict__ Wf, float* __restrict__ sout, int n) {
    int node = blockIdx.x * 4 + (threadIdx.x >> 6);
    if (node >= n) return;
    int lane = threadIdx.x & 63;
    int qq = lane >> 4;
    int sub = lane & 15;
    float acc[8] = {0.f, 0.f, 0.f, 0.f, 0.f, 0.f, 0.f, 0.f};
    float acc2[8] = {0.f, 0.f, 0.f, 0.f, 0.f, 0.f, 0.f, 0.f};
    int beg = row[node], end = row[node + 1];
    int deg = end - beg;
    int t = qq;
    for (; t + 4 < deg; t += 8) {
        unsigned int e0 = edges[beg + t];
        unsigned int e1 = edges[beg + t + 4];
        float w0 = unpackw(e0);
        float w1 = unpackw(e1);
        f16x8 v0 = *(const f16x8*)&H16[(size_t)(e0 >> 15) * F + sub * 8];
        f16x8 v1 = *(const f16x8*)&H16[(size_t)(e1 >> 15) * F + sub * 8];
#pragma unroll
        for (int j = 0; j < 8; j++) {
            acc[j] = fmaf(w0, (float)v0[j], acc[j]);
            acc2[j] = fmaf(w1, (float)v1[j], acc2[j]);
        }
    }
    for (; t < deg; t += 4) {
        unsigned int e0 = edges[beg + t];
        float w0 = unpackw(e0);
        f16x8 v0 = *(const f16x8*)&H16[(size_t)(e0 >> 15) * F + sub * 8];
#pragma unroll
        for (int j = 0; j < 8; j++)
            acc[j] = fmaf(w0, (float)v0[j], acc[j]);
    }
#pragma unroll
    for (int j = 0; j < 8; j++) {
        acc[j] += acc2[j];
        acc[j] += __shfl_xor(acc[j], 16, 64);
        acc[j] += __shfl_xor(acc[j], 32, 64);
    }
    if (lane < 16) {
        float dd = dinv[node];
        f16x8 h = *(const f16x8*)&H16[(size_t)node * F + lane * 8];
        float4 b0 = *(const float4*)&bias[lane * 8];
        float4 b1 = *(const float4*)&bias[lane * 8 + 4];
        float bb[8] = {b0.x, b0.y, b0.z, b0.w, b1.x, b1.y, b1.z, b1.w};
        float4 w0 = *(const float4*)&Wf[lane * 8];
        float4 w1 = *(const float4*)&Wf[lane * 8 + 4];
        float ww[8] = {w0.x, w0.y, w0.z, w0.w, w1.x, w1.y, w1.z, w1.w};
        float p = 0.f;
#pragma unroll
        for (int j = 0; j < 8; j++)
            p += fmaxf(fmaf(dd, acc[j] + (float)h[j], bb[j]), 0.f) * ww[j];
        p += __shfl_xor(p, 8, 64);
        p += __shfl_xor(p, 4, 64);
        p += __shfl_xor(p, 2, 64);
        p += __shfl_xor(p, 1, 64);
        if (lane == 0) sout[node] = dd * p;
    }
}

__global__ void k_aggs(const float* __restrict__ s, const int* __restrict__ row,
                       const unsigned int* __restrict__ edges,
                       const float* __restrict__ dinv, const float* __restrict__ bf,
                       float* __restrict__ out, int n) {
    int i = blockIdx.x * blockDim.x + threadIdx.x;
    if (i >= n) return;
    float dd = dinv[i];
    float ae = s[i];
    int beg = row[i], end = row[i + 1];
    for (int j = beg; j < end; j++) {
        unsigned int p = edges[j];
        ae = fmaf(unpackw(p), s[p >> 15], ae);
    }
    out[i] = fmaf(dd, ae, bf[0]);
}

// ---------------- host launch ----------------

extern "C" void kernel_launch(void* const* d_in, const int* in_sizes, int n_in,
                              void* d_out, int out_size, void* d_ws, size_t ws_size,
                              hipStream_t stream) {
    const float* x    = (const float*)d_in[0];
    const int*   ei   = (const int*)d_in[1];
    const float* ew   = (const float*)d_in[2];
    const float* Win  = (const float*)d_in[3];
    const float* bin  = (const float*)d_in[4];
    const float* Wmid = (const float*)d_in[5];
    const float* bmid = (const float*)d_in[6];
    const float* Wfin = (const float*)d_in[7];
    const float* bfin = (const float*)d_in[8];
    float* out = (float*)d_out;

    char* ws = (char*)d_ws;
    size_t off = 0;
    auto alloc = [&](size_t bytes) -> char* {
        char* p = ws + off;
        off = (off + bytes + 255) & ~(size_t)255;
        return p;
    };
    float* dinv  = (float*)alloc((size_t)N_NODES * 4);
    int*   row   = (int*)alloc((size_t)(N_NODES + 1) * 4);
    int*   pos   = (int*)alloc((size_t)N_NODES * 4);
    unsigned int* edges = (unsigned int*)alloc((size_t)N_EDGES * 4);
    int*   bsum  = (int*)alloc(128 * 4);
    f16*   wtin  = (f16*)alloc(128 * 128 * 2);
    f16*   wtmid = (f16*)alloc(128 * 128 * 2);
    f16*   H16   = (f16*)alloc((size_t)N_NODES * F * 2);   // gemm out (dinv-scaled) / agg in
    f16*   AB16  = (f16*)alloc((size_t)N_NODES * F * 2);   // x16 -> agg out chain
    // aliased into H16's 25.6MB (all consumed before gemm1 writes H16):
    int*  cnt8 = (int*)H16;                                // 3.2 MB
    int*  bc   = cnt8 + (size_t)8 * N_NODES;               // 50000 ints (count -> cursor)
    int*  sbeg = bc + NCB;                                 // 50001 ints (slice starts + sentinel)
    char* stg0 = (char*)(sbeg + NCB + 1);
    int2* stage = (int2*)(((uintptr_t)stg0 + 255) & ~(uintptr_t)255);   // 12.8 MB
    float* sbuf = (float*)AB16;  // aliased: consumed by gemm3 before agg_dot writes

    dim3 b256(256);
    int gN = (N_NODES + 255) / 256;
    int gE = (N_EDGES + 255) / 256;
    int gW = (N_NODES + 3) / 4;
    int gG = (N_NODES + 127) / 128;
    int gS = (N_NODES + 1023) / 1024;        // node scan chunks (98)
    int gS2 = (NCB + 1023) / 1024;           // bucket scan chunks (49)
    int gCB = (NCB + 255) / 256;
    int n16 = (int)(((size_t)8 * N_NODES * 4) / 16);
    int gZ = (n16 + 255) / 256;
    int n8 = N_NODES * F / 8;
    int gC = (n8 + 255) / 256;
    int gPB = (NBK + 3) / 4;

    hipLaunchKernelGGL(k_zero, dim3(gZ), b256, 0, stream, (uint4*)cnt8, n16);
    hipLaunchKernelGGL(k_hist8c, dim3(gE), b256, 0, stream, ei, cnt8, N_EDGES);
    hipLaunchKernelGGL(k_reduce, dim3(gN), b256, 0, stream, cnt8, pos, N_NODES);
    // node scan -> row
    hipLaunchKernelGGL(k_bsum, dim3(gS), b256, 0, stream, pos, bsum, N_NODES);
    hipLaunchKernelGGL(k_bscan, dim3(1), dim3(128), 0, stream, bsum, gS, &row[N_NODES]);
    hipLaunchKernelGGL(k_scan2, dim3(gS), b256, 0, stream, pos, bsum, row, N_NODES);
    // bucket counts + copy-major scan -> sbeg (+ bc becomes cursor)
    hipLaunchKernelGGL(k_bcnt, dim3(gCB), b256, 0, stream, cnt8, bc);
    hipLaunchKernelGGL(k_bsum, dim3(gS2), b256, 0, stream, bc, bsum, NCB);
    hipLaunchKernelGGL(k_bscan, dim3(1), dim3(128), 0, stream, bsum, gS2, &sbeg[NCB]);
    hipLaunchKernelGGL(k_scan2c, dim3(gS2), b256, 0, stream, bc, bsum, sbeg, NCB);
    hipLaunchKernelGGL(k_placeA, dim3(gE), b256, 0, stream, ei, ew, bc, stage, N_EDGES);
    hipLaunchKernelGGL(k_placeB, dim3(gPB), b256, 0, stream, stage, row, sbeg, edges);
    hipLaunchKernelGGL(k_deg, dim3(gN), b256, 0, stream, edges, row, dinv, N_NODES);
    hipLaunchKernelGGL(k_cvt, dim3(gC), b256, 0, stream, x, AB16, n8);
    hipLaunchKernelGGL(k_wt, dim3(1), b256, 0, stream, Win, wtin);
    hipLaunchKernelGGL(k_wt, dim3(1), b256, 0, stream, Wmid, wtmid);

    hipLaunchKernelGGL(k_gemm16, dim3(gG), b256, 0, stream, AB16, wtin, dinv, H16, N_NODES);
    hipLaunchKernelGGL(k_agg, dim3(gW), b256, 0, stream, H16, row, edges, dinv, bin, AB16, N_NODES);
    hipLaunchKernelGGL(k_gemm16, dim3(gG), b256, 0, stream, AB16, wtmid, dinv, H16, N_NODES);
    hipLaunchKernelGGL(k_agg, dim3(gW), b256, 0, stream, H16, row, edges, dinv, bmid, AB16, N_NODES);
    hipLaunchKernelGGL(k_gemm16, dim3(gG), b256, 0, stream, AB16, wtmid, dinv, H16, N_NODES);
    hipLaunchKernelGGL(k_agg_dot, dim3(gW), b256, 0, stream, H16, row, edges, dinv, bmid, Wfin, sbuf, N_NODES);
    hipLaunchKernelGGL(k_aggs, dim3(gN), b256, 0, stream, sbuf, row, edges, dinv, bfin, out, N_NODES);
}

// Round 13
// 479.208 us; speedup vs baseline: 1.1610x; 1.1610x over previous
//
#include <hip/hip_runtime.h>
#include <stdint.h>

#define N_NODES 100000
#define N_EDGES 1600000
#define F 128
#define CBN 512                    // nodes per coarse bucket
#define NCBK 196                   // ceil(N_NODES/CBN)
#define CHUNK 4096                 // edges per binA block
#define BUFCAP 10240               // binB LDS edge buffer (mean 8192 + 22 sigma)

typedef _Float16 f16;
typedef _Float16 f16x4 __attribute__((ext_vector_type(4)));
typedef _Float16 f16x8 __attribute__((ext_vector_type(8)));
typedef float f32x4 __attribute__((ext_vector_type(4)));

// edge pack: (src << 15) | (fp16 bits of w, sign bit dropped — w in [0,1))
__device__ inline float unpackw(unsigned int p) {
    unsigned short b = (unsigned short)(p & 0x7FFF);
    return (float)__builtin_bit_cast(f16, b);
}

// ---------------- XCD-privatized count histogram (copy = blockIdx & 7) ----------------

__global__ void k_zero(uint4* p, int n16) {
    int i = blockIdx.x * blockDim.x + threadIdx.x;
    if (i < n16) p[i] = make_uint4(0, 0, 0, 0);
}

__global__ void k_hist8c(const int* __restrict__ ei, int* __restrict__ cnt8, int e) {
    int i = blockIdx.x * blockDim.x + threadIdx.x;
    if (i < e) {
        int d = ei[N_EDGES + i];
        int c = blockIdx.x & 7;
        atomicAdd(&cnt8[(size_t)c * N_NODES + d], 1);
    }
}

// fused: reduce 8 histogram copies -> pos[] AND per-1024-chunk block sums
__launch_bounds__(256)
__global__ void k_bsumF(const int* __restrict__ cnt8, int* __restrict__ pos,
                        int* __restrict__ bsum, int n) {
    int b = blockIdx.x, tid = threadIdx.x;
    int base = b * 1024 + tid * 4;
    int s = 0;
#pragma unroll
    for (int j = 0; j < 4; j++) {
        int idx = base + j;
        if (idx < n) {
            int c = 0;
#pragma unroll
            for (int k = 0; k < 8; k++) c += cnt8[(size_t)k * N_NODES + idx];
            pos[idx] = c;
            s += c;
        }
    }
    for (int off = 32; off; off >>= 1) s += __shfl_down(s, off, 64);
    __shared__ int ws[4];
    if ((tid & 63) == 0) ws[tid >> 6] = s;
    __syncthreads();
    if (tid == 0) bsum[b] = ws[0] + ws[1] + ws[2] + ws[3];
}

__launch_bounds__(128)
__global__ void k_bscan(int* bsum, int nb, int* total_out) {
    __shared__ int ls[128];
    int tid = threadIdx.x;
    int v = (tid < nb) ? bsum[tid] : 0;
    ls[tid] = v;
    __syncthreads();
    for (int off = 1; off < 128; off <<= 1) {
        int t = (tid >= off) ? ls[tid - off] : 0;
        __syncthreads();
        ls[tid] += t;
        __syncthreads();
    }
    int ex = tid ? ls[tid - 1] : 0;
    if (tid < nb) bsum[tid] = ex;
    if (tid == 0) *total_out = N_EDGES;
}

// node scan: writes row + coarse-bucket cursors (row at each CBN boundary)
__launch_bounds__(256)
__global__ void k_scan2(int* __restrict__ cnt_pos, const int* __restrict__ boff,
                        int* __restrict__ row, int* __restrict__ gcur, int n) {
    __shared__ int ls[256];
    int b = blockIdx.x, tid = threadIdx.x;
    int base = b * 1024 + tid * 4;
    int v[4];
    int s = 0;
#pragma unroll
    for (int j = 0; j < 4; j++) {
        v[j] = (base + j < n) ? cnt_pos[base + j] : 0;
        s += v[j];
    }
    ls[tid] = s;
    __syncthreads();
    for (int off = 1; off < 256; off <<= 1) {
        int t = (tid >= off) ? ls[tid - off] : 0;
        __syncthreads();
        ls[tid] += t;
        __syncthreads();
    }
    int run = boff[b] + (tid ? ls[tid - 1] : 0);
#pragma unroll
    for (int j = 0; j < 4; j++) {
        int node = base + j;
        if (node < n) {
            row[node] = run;
            if ((node & (CBN - 1)) == 0) gcur[node >> 9] = run;
            run += v[j];
        }
    }
}

// ---------------- LDS write-combining binner (R13) ----------------
// Measured R9-R12: scattered/temporally-sparse partial-line writes cost ~5x
// write amplification (64B writeback per touch). binA converts per-edge
// scatter into per-(block,bin) contiguous runs claimed with one atomic.

__launch_bounds__(256)
__global__ void k_binA(const int* __restrict__ ei, const float* __restrict__ w,
                       int* __restrict__ gcur, int2* __restrict__ stage, int e) {
    __shared__ int hist[256];
    __shared__ int bst[257];
    __shared__ int gb[256];
    __shared__ int ls[256];
    __shared__ int rec[CHUNK];
    __shared__ int meta[CHUNK];
    int tid = threadIdx.x;
    int base = blockIdx.x * CHUNK;
    int cnt = min(CHUNK, e - base);
    hist[tid] = 0;
    __syncthreads();

    int ew_[16], mr_[16];
    int nloc = 0;
    if (cnt == CHUNK) {
#pragma unroll
        for (int k = 0; k < 16; k++) {
            int i = base + tid + k * 256;
            int s = ei[i];
            int d = ei[N_EDGES + i];
            f16 hw = (f16)w[i];
            unsigned short wb = __builtin_bit_cast(unsigned short, hw);
            ew_[k] = (int)(((unsigned int)s << 15) | (wb & 0x7FFF));
            int cb = d >> 9;
            int local = d & (CBN - 1);
            int r = atomicAdd(&hist[cb], 1);
            mr_[k] = (cb << 22) | (local << 13) | r;   // cb:8 local:9 r:13
        }
        nloc = 16;
    } else {
        for (int i = tid; i < cnt; i += 256) {
            int s = ei[base + i];
            int d = ei[N_EDGES + base + i];
            f16 hw = (f16)w[base + i];
            unsigned short wb = __builtin_bit_cast(unsigned short, hw);
            ew_[nloc] = (int)(((unsigned int)s << 15) | (wb & 0x7FFF));
            int cb = d >> 9;
            int local = d & (CBN - 1);
            int r = atomicAdd(&hist[cb], 1);
            mr_[nloc] = (cb << 22) | (local << 13) | r;
            nloc++;
        }
    }
    __syncthreads();
    // exclusive scan of hist -> bst
    int v = hist[tid];
    ls[tid] = v;
    __syncthreads();
    for (int off = 1; off < 256; off <<= 1) {
        int t = (tid >= off) ? ls[tid - off] : 0;
        __syncthreads();
        ls[tid] += t;
        __syncthreads();
    }
    bst[tid] = ls[tid] - v;
    if (tid == 255) bst[256] = ls[255];
    __syncthreads();
    // scatter registers -> LDS in bin order
    for (int k = 0; k < nloc; k++) {
        int m = mr_[k];
        int cb = m >> 22;
        int pos = bst[cb] + (m & 0x1FFF);
        rec[pos] = ew_[k];
        meta[pos] = (cb << 9) | ((m >> 13) & 0x1FF);
    }
    __syncthreads();
    // claim one contiguous global range per bin
    if (tid < NCBK) {
        int c = bst[tid + 1] - bst[tid];
        gb[tid] = c ? atomicAdd(&gcur[tid], c) : 0;
    }
    __syncthreads();
    // copy out bin-ordered: contiguous runs per bin -> mostly full-line writes
    for (int j = tid; j < cnt; j += 256) {
        int m = meta[j];
        int cb = m >> 9;
        stage[gb[cb] + (j - bst[cb])] = make_int2(m & 511, rec[j]);
    }
}

// binB: one block per coarse bucket; permute to exact CSR order in LDS, then
// one coalesced window write. k_deg fused (dinv from LDS buffer).
__launch_bounds__(256)
__global__ void k_binB(const int2* __restrict__ stage, const int* __restrict__ row,
                       unsigned int* __restrict__ edges, float* __restrict__ dinv) {
    __shared__ int cur[CBN];
    __shared__ unsigned int buf[BUFCAP];
    int tid = threadIdx.x;
    int cb = blockIdx.x;
    int n0 = cb * CBN;
    int nn = min(CBN, N_NODES - n0);
    int base = row[n0];
    int hi = row[n0 + nn];
    for (int l = tid; l < nn; l += 256) cur[l] = row[n0 + l] - base;
    __syncthreads();
    for (int j = base + tid; j < hi; j += 256) {
        int2 r = stage[j];
        int p = atomicAdd(&cur[r.x], 1);
        buf[p] = (unsigned int)r.y;
    }
    __syncthreads();
    int range = hi - base;
    for (int j = tid; j < range; j += 256)
        edges[base + j] = buf[j];
    for (int l = tid; l < nn; l += 256) {
        int lo = row[n0 + l] - base;
        int h2 = row[n0 + l + 1] - base;
        float s = 1.0f;
        for (int j = lo; j < h2; j++) s += unpackw(buf[j]);
        dinv[n0 + l] = rsqrtf(s);
    }
}

// ---------------- fp32 -> fp16 conversions ----------------

__global__ void k_cvt(const float* __restrict__ X, f16* __restrict__ Y, int n8) {
    int i = blockIdx.x * blockDim.x + threadIdx.x;
    if (i < n8) {
        float4 a = ((const float4*)X)[i * 2];
        float4 b = ((const float4*)X)[i * 2 + 1];
        f16x8 o;
        o[0] = (f16)a.x; o[1] = (f16)a.y; o[2] = (f16)a.z; o[3] = (f16)a.w;
        o[4] = (f16)b.x; o[5] = (f16)b.y; o[6] = (f16)b.z; o[7] = (f16)b.w;
        ((f16x8*)Y)[i] = o;
    }
}

// both weight transposes in one launch (blockIdx selects matrix)
__global__ void k_wt2(const float* __restrict__ Wa, const float* __restrict__ Wb,
                      f16* __restrict__ Wta, f16* __restrict__ Wtb) {
    const float* W = blockIdx.x ? Wb : Wa;
    f16* Wt = blockIdx.x ? Wtb : Wta;
    int t = threadIdx.x;
#pragma unroll
    for (int it = 0; it < 64; it++) {
        int idx = t + it * 256;
        int k = idx >> 7, n = idx & 127;
        Wt[n * 128 + k] = (f16)W[idx];
    }
}

// ---------------- fp16 MFMA GEMM, epilogue scales rows by dinv ----------------

#define LDK 136

__launch_bounds__(256, 2)
__global__ void k_gemm16(const f16* __restrict__ A, const f16* __restrict__ Wt,
                         const float* __restrict__ dinv, f16* __restrict__ H, int nrows) {
    __shared__ f16 Ws[128 * LDK];
    int tid = threadIdx.x;
    int r0 = blockIdx.x * 128;
    int wave = tid >> 6;
    int lane = tid & 63;
    int lrow = lane & 15;
    int quad = lane >> 4;

    f16x8 a[2][4];
#pragma unroll
    for (int mt = 0; mt < 2; mt++) {
        int row = r0 + wave * 32 + mt * 16 + lrow;
#pragma unroll
        for (int kc = 0; kc < 4; kc++) {
            if (row < nrows)
                a[mt][kc] = *(const f16x8*)&A[(size_t)row * F + kc * 32 + quad * 8];
            else
                a[mt][kc] = (f16x8){};
        }
    }
#pragma unroll
    for (int it = 0; it < 8; it++) {
        int c = tid + it * 256;
        int rw = c >> 4;
        int off = (c & 15) * 8;
        *(f16x8*)&Ws[rw * LDK + off] = *(const f16x8*)&Wt[rw * 128 + off];
    }
    __syncthreads();

    f32x4 acc[2][8] = {};
#pragma unroll
    for (int kc = 0; kc < 4; kc++) {
        f16x8 b[8];
#pragma unroll
        for (int nt = 0; nt < 8; nt++)
            b[nt] = *(const f16x8*)&Ws[(nt * 16 + lrow) * LDK + kc * 32 + quad * 8];
#pragma unroll
        for (int nt = 0; nt < 8; nt++) {
            acc[0][nt] = __builtin_amdgcn_mfma_f32_16x16x32_f16(a[0][kc], b[nt], acc[0][nt], 0, 0, 0);
            acc[1][nt] = __builtin_amdgcn_mfma_f32_16x16x32_f16(a[1][kc], b[nt], acc[1][nt], 0, 0, 0);
        }
    }
    __syncthreads();
#pragma unroll
    for (int mt = 0; mt < 2; mt++) {
#pragma unroll
        for (int r = 0; r < 4; r++) {
            int lr = wave * 32 + mt * 16 + quad * 4 + r;
            int grow = r0 + lr;
            float dv = (grow < nrows) ? dinv[grow] : 0.f;
#pragma unroll
            for (int nt = 0; nt < 8; nt++)
                Ws[lr * 132 + nt * 16 + lrow] = (f16)(acc[mt][nt][r] * dv);
        }
    }
    __syncthreads();
#pragma unroll
    for (int it = 0; it < 8; it++) {
        int c = it * 256 + tid;
        int rw = c >> 4;
        int col = (c & 15) * 8;
        int grow = r0 + rw;
        if (grow < nrows)
            *(f16x8*)&H[(size_t)grow * F + col] = *(const f16x8*)&Ws[rw * 132 + col];
    }
}

// ---------------- aggregation: quarter-wave 16B gathers, no per-edge dinv ----------------

__launch_bounds__(256)
__global__ void k_agg(const f16* __restrict__ H16, const int* __restrict__ row,
                      const unsigned int* __restrict__ edges,
                      const float* __restrict__ dinv, const float* __restrict__ bias,
                      f16* __restrict__ out, int n) {
    int node = blockIdx.x * 4 + (threadIdx.x >> 6);
    if (node >= n) return;
    int lane = threadIdx.x & 63;
    int qq = lane >> 4;
    int sub = lane & 15;
    float acc[8] = {0.f, 0.f, 0.f, 0.f, 0.f, 0.f, 0.f, 0.f};
    float acc2[8] = {0.f, 0.f, 0.f, 0.f, 0.f, 0.f, 0.f, 0.f};
    int beg = row[node], end = row[node + 1];
    int deg = end - beg;
    int t = qq;
    for (; t + 4 < deg; t += 8) {
        unsigned int e0 = edges[beg + t];
        unsigned int e1 = edges[beg + t + 4];
        float w0 = unpackw(e0);
        float w1 = unpackw(e1);
        f16x8 v0 = *(const f16x8*)&H16[(size_t)(e0 >> 15) * F + sub * 8];
        f16x8 v1 = *(const f16x8*)&H16[(size_t)(e1 >> 15) * F + sub * 8];
#pragma unroll
        for (int j = 0; j < 8; j++) {
            acc[j] = fmaf(w0, (float)v0[j], acc[j]);
            acc2[j] = fmaf(w1, (float)v1[j], acc2[j]);
        }
    }
    for (; t < deg; t += 4) {
        unsigned int e0 = edges[beg + t];
        float w0 = unpackw(e0);
        f16x8 v0 = *(const f16x8*)&H16[(size_t)(e0 >> 15) * F + sub * 8];
#pragma unroll
        for (int j = 0; j < 8; j++)
            acc[j] = fmaf(w0, (float)v0[j], acc[j]);
    }
#pragma unroll
    for (int j = 0; j < 8; j++) {
        acc[j] += acc2[j];
        acc[j] += __shfl_xor(acc[j], 16, 64);
        acc[j] += __shfl_xor(acc[j], 32, 64);
    }
    if (lane < 16) {
        float dd = dinv[node];
        f16x8 h = *(const f16x8*)&H16[(size_t)node * F + lane * 8];
        float4 b0 = *(const float4*)&bias[lane * 8];
        float4 b1 = *(const float4*)&bias[lane * 8 + 4];
        float bb[8] = {b0.x, b0.y, b0.z, b0.w, b1.x, b1.y, b1.z, b1.w};
        f16x8 o;
#pragma unroll
        for (int j = 0; j < 8; j++) {
            float r = fmaxf(fmaf(dd, acc[j] + (float)h[j], bb[j]), 0.f);
            o[j] = (f16)r;
        }
        *(f16x8*)&out[(size_t)node * F + lane * 8] = o;
    }
}

// agg3 fused with final dot: s'[node] = dinv[node] * ( relu(agg3) . Wfin )
__launch_bounds__(256)
__global__ void k_agg_dot(const f16* __restrict__ H16, const int* __restrict__ row,
                          const unsigned int* __restrict__ edges,
                          const float* __restrict__ dinv, const float* __restrict__ bias,
                          const float* __restrict__ Wf, float* __restrict__ sout, int n) {
    int node = blockIdx.x * 4 + (threadIdx.x >> 6);
    if (node >= n) return;
    int lane = threadIdx.x & 63;
    int qq = lane >> 4;
    int sub = lane & 15;
    float acc[8] = {0.f, 0.f, 0.f, 0.f, 0.f, 0.f, 0.f, 0.f};
    float acc2[8] = {0.f, 0.f, 0.f, 0.f, 0.f, 0.f, 0.f, 0.f};
    int beg = row[node], end = row[node + 1];
    int deg = end - beg;
    int t = qq;
    for (; t + 4 < deg; t += 8) {
        unsigned int e0 = edges[beg + t];
        unsigned int e1 = edges[beg + t + 4];
        float w0 = unpackw(e0);
        float w1 = unpackw(e1);
        f16x8 v0 = *(const f16x8*)&H16[(size_t)(e0 >> 15) * F + sub * 8];
        f16x8 v1 = *(const f16x8*)&H16[(size_t)(e1 >> 15) * F + sub * 8];
#pragma unroll
        for (int j = 0; j < 8; j++) {
            acc[j] = fmaf(w0, (float)v0[j], acc[j]);
            acc2[j] = fmaf(w1, (float)v1[j], acc2[j]);
        }
    }
    for (; t < deg; t += 4) {
        unsigned int e0 = edges[beg + t];
        float w0 = unpackw(e0);
        f16x8 v0 = *(const f16x8*)&H16[(size_t)(e0 >> 15) * F + sub * 8];
#pragma unroll
        for (int j = 0; j < 8; j++)
            acc[j] = fmaf(w0, (float)v0[j], acc[j]);
    }
#pragma unroll
    for (int j = 0; j < 8; j++) {
        acc[j] += acc2[j];
        acc[j] += __shfl_xor(acc[j], 16, 64);
        acc[j] += __shfl_xor(acc[j], 32, 64);
    }
    if (lane < 16) {
        float dd = dinv[node];
        f16x8 h = *(const f16x8*)&H16[(size_t)node * F + lane * 8];
        float4 b0 = *(const float4*)&bias[lane * 8];
        float4 b1 = *(const float4*)&bias[lane * 8 + 4];
        float bb[8] = {b0.x, b0.y, b0.z, b0.w, b1.x, b1.y, b1.z, b1.w};
        float4 w0 = *(const float4*)&Wf[lane * 8];
        float4 w1 = *(const float4*)&Wf[lane * 8 + 4];
        float ww[8] = {w0.x, w0.y, w0.z, w0.w, w1.x, w1.y, w1.z, w1.w};
        float p = 0.f;
#pragma unroll
        for (int j = 0; j < 8; j++)
            p += fmaxf(fmaf(dd, acc[j] + (float)h[j], bb[j]), 0.f) * ww[j];
        p += __shfl_xor(p, 8, 64);
        p += __shfl_xor(p, 4, 64);
        p += __shfl_xor(p, 2, 64);
        p += __shfl_xor(p, 1, 64);
        if (lane == 0) sout[node] = dd * p;
    }
}

__global__ void k_aggs(const float* __restrict__ s, const int* __restrict__ row,
                       const unsigned int* __restrict__ edges,
                       const float* __restrict__ dinv, const float* __restrict__ bf,
                       float* __restrict__ out, int n) {
    int i = blockIdx.x * blockDim.x + threadIdx.x;
    if (i >= n) return;
    float dd = dinv[i];
    float ae = s[i];
    int beg = row[i], end = row[i + 1];
    for (int j = beg; j < end; j++) {
        unsigned int p = edges[j];
        ae = fmaf(unpackw(p), s[p >> 15], ae);
    }
    out[i] = fmaf(dd, ae, bf[0]);
}

// ---------------- host launch ----------------

extern "C" void kernel_launch(void* const* d_in, const int* in_sizes, int n_in,
                              void* d_out, int out_size, void* d_ws, size_t ws_size,
                              hipStream_t stream) {
    const float* x    = (const float*)d_in[0];
    const int*   ei   = (const int*)d_in[1];
    const float* ew   = (const float*)d_in[2];
    const float* Win  = (const float*)d_in[3];
    const float* bin  = (const float*)d_in[4];
    const float* Wmid = (const float*)d_in[5];
    const float* bmid = (const float*)d_in[6];
    const float* Wfin = (const float*)d_in[7];
    const float* bfin = (const float*)d_in[8];
    float* out = (float*)d_out;

    char* ws = (char*)d_ws;
    size_t off = 0;
    auto alloc = [&](size_t bytes) -> char* {
        char* p = ws + off;
        off = (off + bytes + 255) & ~(size_t)255;
        return p;
    };
    float* dinv  = (float*)alloc((size_t)N_NODES * 4);
    int*   row   = (int*)alloc((size_t)(N_NODES + 1) * 4);
    int*   pos   = (int*)alloc((size_t)N_NODES * 4);
    unsigned int* edges = (unsigned int*)alloc((size_t)N_EDGES * 4);
    int*   bsum  = (int*)alloc(128 * 4);
    int*   gcur  = (int*)alloc(256 * 4);
    f16*   wtin  = (f16*)alloc(128 * 128 * 2);
    f16*   wtmid = (f16*)alloc(128 * 128 * 2);
    f16*   H16   = (f16*)alloc((size_t)N_NODES * F * 2);   // gemm out (dinv-scaled) / agg in
    f16*   AB16  = (f16*)alloc((size_t)N_NODES * F * 2);   // x16 -> agg out chain
    // aliased into H16's 25.6MB (all consumed before gemm1 writes H16):
    int*  cnt8 = (int*)H16;                                           // 3.2 MB
    int2* stage = (int2*)((char*)H16 + (size_t)8 * N_NODES * 4 + 256); // 12.8 MB
    float* sbuf = (float*)AB16;  // aliased: consumed by gemm3 before agg_dot writes

    dim3 b256(256);
    int gN = (N_NODES + 255) / 256;
    int gE = (N_EDGES + 255) / 256;
    int gW = (N_NODES + 3) / 4;
    int gG = (N_NODES + 127) / 128;
    int gS = (N_NODES + 1023) / 1024;
    int n16 = (int)(((size_t)8 * N_NODES * 4) / 16);
    int gZ = (n16 + 255) / 256;
    int n8 = N_NODES * F / 8;
    int gC = (n8 + 255) / 256;
    int gA = (N_EDGES + CHUNK - 1) / CHUNK;   // 391

    hipLaunchKernelGGL(k_zero, dim3(gZ), b256, 0, stream, (uint4*)cnt8, n16);
    hipLaunchKernelGGL(k_hist8c, dim3(gE), b256, 0, stream, ei, cnt8, N_EDGES);
    hipLaunchKernelGGL(k_bsumF, dim3(gS), b256, 0, stream, cnt8, pos, bsum, N_NODES);
    hipLaunchKernelGGL(k_bscan, dim3(1), dim3(128), 0, stream, bsum, gS, &row[N_NODES]);
    hipLaunchKernelGGL(k_scan2, dim3(gS), b256, 0, stream, pos, bsum, row, gcur, N_NODES);
    hipLaunchKernelGGL(k_binA, dim3(gA), b256, 0, stream, ei, ew, gcur, stage, N_EDGES);
    hipLaunchKernelGGL(k_binB, dim3(NCBK), b256, 0, stream, stage, row, edges, dinv);
    hipLaunchKernelGGL(k_cvt, dim3(gC), b256, 0, stream, x, AB16, n8);
    hipLaunchKernelGGL(k_wt2, dim3(2), b256, 0, stream, Win, Wmid, wtin, wtmid);

    hipLaunchKernelGGL(k_gemm16, dim3(gG), b256, 0, stream, AB16, wtin, dinv, H16, N_NODES);
    hipLaunchKernelGGL(k_agg, dim3(gW), b256, 0, stream, H16, row, edges, dinv, bin, AB16, N_NODES);
    hipLaunchKernelGGL(k_gemm16, dim3(gG), b256, 0, stream, AB16, wtmid, dinv, H16, N_NODES);
    hipLaunchKernelGGL(k_agg, dim3(gW), b256, 0, stream, H16, row, edges, dinv, bmid, AB16, N_NODES);
    hipLaunchKernelGGL(k_gemm16, dim3(gG), b256, 0, stream, AB16, wtmid, dinv, H16, N_NODES);
    hipLaunchKernelGGL(k_agg_dot, dim3(gW), b256, 0, stream, H16, row, edges, dinv, bmid, Wfin, sbuf, N_NODES);
    hipLaunchKernelGGL(k_aggs, dim3(gN), b256, 0, stream, sbuf, row, edges, dinv, bfin, out, N_NODES);
}

// Round 14
// 415.539 us; speedup vs baseline: 1.3388x; 1.1532x over previous
//
#include <hip/hip_runtime.h>
#include <stdint.h>

#define N_NODES 100000
#define N_EDGES 1600000
#define F 128
#define CBN 512                    // nodes per coarse bucket
#define NCBK 196                   // ceil(N_NODES/CBN)
#define CHUNK 4096                 // edges per binA/bhist block
#define BUFCAP 10240               // binB LDS edge buffer (mean 8192 + ~22 sigma)

typedef _Float16 f16;
typedef _Float16 f16x4 __attribute__((ext_vector_type(4)));
typedef _Float16 f16x8 __attribute__((ext_vector_type(8)));
typedef float f32x4 __attribute__((ext_vector_type(4)));

// edge pack: (src << 15) | (fp16 bits of w, sign bit dropped — w in [0,1))
__device__ inline float unpackw(unsigned int p) {
    unsigned short b = (unsigned short)(p & 0x7FFF);
    return (float)__builtin_bit_cast(f16, b);
}

// ---------------- R14 front-end: 196-bucket histogram only ----------------
// (R13's 100k-node histogram + 3-phase scan deleted: binB now derives per-node
// row[] itself from its bucket's edges in LDS.)

__global__ void k_zero0(int* bktcnt) {
    int i = threadIdx.x;
    if (i < NCBK) bktcnt[i] = 0;
}

// LDS histogram of dst>>9 per 4096-edge chunk, one global atomic per (block,bucket)
__launch_bounds__(256)
__global__ void k_bhist(const int* __restrict__ ei, int* __restrict__ bktcnt, int e) {
    __shared__ int h[NCBK];
    int tid = threadIdx.x;
    if (tid < NCBK) h[tid] = 0;
    __syncthreads();
    int base = blockIdx.x * CHUNK;
    int cnt = min(CHUNK, e - base);
    const int* dst = ei + N_EDGES + base;
    if (cnt == CHUNK) {
        const int4* d4 = (const int4*)dst;
#pragma unroll
        for (int k = 0; k < 4; k++) {
            int4 v = d4[tid + k * 256];
            atomicAdd(&h[v.x >> 9], 1);
            atomicAdd(&h[v.y >> 9], 1);
            atomicAdd(&h[v.z >> 9], 1);
            atomicAdd(&h[v.w >> 9], 1);
        }
    } else {
        for (int i = tid; i < cnt; i += 256)
            atomicAdd(&h[dst[i] >> 9], 1);
    }
    __syncthreads();
    if (tid < NCBK && h[tid]) atomicAdd(&bktcnt[tid], h[tid]);
}

// one block: exclusive scan of 196 bucket counts -> gbase[197], init gcur, row[N]
__launch_bounds__(256)
__global__ void k_bktscan(const int* __restrict__ bktcnt, int* __restrict__ gbase,
                          int* __restrict__ gcur, int* __restrict__ row) {
    __shared__ int ls[256];
    int tid = threadIdx.x;
    int v = (tid < NCBK) ? bktcnt[tid] : 0;
    ls[tid] = v;
    __syncthreads();
    for (int off = 1; off < 256; off <<= 1) {
        int t = (tid >= off) ? ls[tid - off] : 0;
        __syncthreads();
        ls[tid] += t;
        __syncthreads();
    }
    int ex = ls[tid] - v;
    if (tid < NCBK) { gbase[tid] = ex; gcur[tid] = ex; }
    if (tid == NCBK) gbase[NCBK] = N_EDGES;
    if (tid == 0) row[N_NODES] = N_EDGES;
}

// ---------------- LDS write-combining binner (R13, proven) ----------------
// Measured R9-R12: scattered/temporally-sparse partial-line writes cost ~5x
// write amplification. binA converts per-edge scatter into per-(block,bin)
// contiguous runs claimed with one atomic each.

__launch_bounds__(256)
__global__ void k_binA(const int* __restrict__ ei, const float* __restrict__ w,
                       int* __restrict__ gcur, int2* __restrict__ stage, int e) {
    __shared__ int hist[256];
    __shared__ int bst[257];
    __shared__ int gb[256];
    __shared__ int ls[256];
    __shared__ int rec[CHUNK];
    __shared__ int meta[CHUNK];
    int tid = threadIdx.x;
    int base = blockIdx.x * CHUNK;
    int cnt = min(CHUNK, e - base);
    hist[tid] = 0;
    __syncthreads();

    int ew_[16], mr_[16];
    int nloc = 0;
    if (cnt == CHUNK) {
#pragma unroll
        for (int k = 0; k < 16; k++) {
            int i = base + tid + k * 256;
            int s = ei[i];
            int d = ei[N_EDGES + i];
            f16 hw = (f16)w[i];
            unsigned short wb = __builtin_bit_cast(unsigned short, hw);
            ew_[k] = (int)(((unsigned int)s << 15) | (wb & 0x7FFF));
            int cb = d >> 9;
            int local = d & (CBN - 1);
            int r = atomicAdd(&hist[cb], 1);
            mr_[k] = (cb << 22) | (local << 13) | r;   // cb:8 local:9 r:13
        }
        nloc = 16;
    } else {
        for (int i = tid; i < cnt; i += 256) {
            int s = ei[base + i];
            int d = ei[N_EDGES + base + i];
            f16 hw = (f16)w[base + i];
            unsigned short wb = __builtin_bit_cast(unsigned short, hw);
            ew_[nloc] = (int)(((unsigned int)s << 15) | (wb & 0x7FFF));
            int cb = d >> 9;
            int local = d & (CBN - 1);
            int r = atomicAdd(&hist[cb], 1);
            mr_[nloc] = (cb << 22) | (local << 13) | r;
            nloc++;
        }
    }
    __syncthreads();
    int v = hist[tid];
    ls[tid] = v;
    __syncthreads();
    for (int off = 1; off < 256; off <<= 1) {
        int t = (tid >= off) ? ls[tid - off] : 0;
        __syncthreads();
        ls[tid] += t;
        __syncthreads();
    }
    bst[tid] = ls[tid] - v;
    if (tid == 255) bst[256] = ls[255];
    __syncthreads();
    for (int k = 0; k < nloc; k++) {
        int m = mr_[k];
        int cb = m >> 22;
        int pos = bst[cb] + (m & 0x1FFF);
        rec[pos] = ew_[k];
        meta[pos] = (cb << 9) | ((m >> 13) & 0x1FF);
    }
    __syncthreads();
    if (tid < NCBK) {
        int c = bst[tid + 1] - bst[tid];
        gb[tid] = c ? atomicAdd(&gcur[tid], c) : 0;
    }
    __syncthreads();
    for (int j = tid; j < cnt; j += 256) {
        int m = meta[j];
        int cb = m >> 9;
        stage[gb[cb] + (j - bst[cb])] = make_int2(m & 511, rec[j]);
    }
}

// binB: one block per coarse bucket. Derives per-node row[] itself:
// pass1 count locals -> LDS scan -> row write; pass2 permute to CSR in LDS;
// coalesced final write + fused dinv.
__launch_bounds__(256)
__global__ void k_binB(const int2* __restrict__ stage, const int* __restrict__ gbase,
                       unsigned int* __restrict__ edges, int* __restrict__ row,
                       float* __restrict__ dinv) {
    __shared__ int cnt[CBN];
    __shared__ int ex[CBN + 1];
    __shared__ int cur[CBN];
    __shared__ int ls[256];
    __shared__ unsigned int buf[BUFCAP];
    int tid = threadIdx.x;
    int cb = blockIdx.x;
    int n0 = cb * CBN;
    int nn = min(CBN, N_NODES - n0);
    int base = gbase[cb];
    int hi = gbase[cb + 1];
    cnt[tid] = 0;
    cnt[tid + 256] = 0;
    __syncthreads();
    // pass 1: local histogram
    for (int j = base + tid; j < hi; j += 256)
        atomicAdd(&cnt[stage[j].x], 1);
    __syncthreads();
    // exclusive scan of 512 (2 per thread)
    int a = cnt[2 * tid], b = cnt[2 * tid + 1];
    int s = a + b;
    ls[tid] = s;
    __syncthreads();
    for (int off = 1; off < 256; off <<= 1) {
        int t = (tid >= off) ? ls[tid - off] : 0;
        __syncthreads();
        ls[tid] += t;
        __syncthreads();
    }
    int bx = ls[tid] - s;
    ex[2 * tid] = bx;
    ex[2 * tid + 1] = bx + a;
    cur[2 * tid] = bx;
    cur[2 * tid + 1] = bx + a;
    if (tid == 255) ex[512] = ls[255];
    __syncthreads();
    // row write (row[n0+nn] is the next block's base; row[N] by k_bktscan)
    for (int l = tid; l < nn; l += 256) row[n0 + l] = base + ex[l];
    // pass 2: permute to CSR order in LDS
    for (int j = base + tid; j < hi; j += 256) {
        int2 r = stage[j];
        int p = atomicAdd(&cur[r.x], 1);
        buf[p] = (unsigned int)r.y;
    }
    __syncthreads();
    int range = hi - base;
    for (int j = tid; j < range; j += 256)
        edges[base + j] = buf[j];
    // fused dinv: deg = 1 + sum w over the node's CSR slice (in LDS)
    for (int l = tid; l < nn; l += 256) {
        int lo = ex[l];
        int h2 = ex[l + 1];
        float sm = 1.0f;
        for (int j = lo; j < h2; j++) sm += unpackw(buf[j]);
        dinv[n0 + l] = rsqrtf(sm);
    }
}

// ---------------- fp32 -> fp16 conversions ----------------

__global__ void k_cvt(const float* __restrict__ X, f16* __restrict__ Y, int n8) {
    int i = blockIdx.x * blockDim.x + threadIdx.x;
    if (i < n8) {
        float4 a = ((const float4*)X)[i * 2];
        float4 b = ((const float4*)X)[i * 2 + 1];
        f16x8 o;
        o[0] = (f16)a.x; o[1] = (f16)a.y; o[2] = (f16)a.z; o[3] = (f16)a.w;
        o[4] = (f16)b.x; o[5] = (f16)b.y; o[6] = (f16)b.z; o[7] = (f16)b.w;
        ((f16x8*)Y)[i] = o;
    }
}

__global__ void k_wt2(const float* __restrict__ Wa, const float* __restrict__ Wb,
                      f16* __restrict__ Wta, f16* __restrict__ Wtb) {
    const float* W = blockIdx.x ? Wb : Wa;
    f16* Wt = blockIdx.x ? Wtb : Wta;
    int t = threadIdx.x;
#pragma unroll
    for (int it = 0; it < 64; it++) {
        int idx = t + it * 256;
        int k = idx >> 7, n = idx & 127;
        Wt[n * 128 + k] = (f16)W[idx];
    }
}

// ---------------- fp16 MFMA GEMM, epilogue scales rows by dinv ----------------

#define LDK 136

__launch_bounds__(256, 2)
__global__ void k_gemm16(const f16* __restrict__ A, const f16* __restrict__ Wt,
                         const float* __restrict__ dinv, f16* __restrict__ H, int nrows) {
    __shared__ f16 Ws[128 * LDK];
    int tid = threadIdx.x;
    int r0 = blockIdx.x * 128;
    int wave = tid >> 6;
    int lane = tid & 63;
    int lrow = lane & 15;
    int quad = lane >> 4;

    f16x8 a[2][4];
#pragma unroll
    for (int mt = 0; mt < 2; mt++) {
        int row = r0 + wave * 32 + mt * 16 + lrow;
#pragma unroll
        for (int kc = 0; kc < 4; kc++) {
            if (row < nrows)
                a[mt][kc] = *(const f16x8*)&A[(size_t)row * F + kc * 32 + quad * 8];
            else
                a[mt][kc] = (f16x8){};
        }
    }
#pragma unroll
    for (int it = 0; it < 8; it++) {
        int c = tid + it * 256;
        int rw = c >> 4;
        int off = (c & 15) * 8;
        *(f16x8*)&Ws[rw * LDK + off] = *(const f16x8*)&Wt[rw * 128 + off];
    }
    __syncthreads();

    f32x4 acc[2][8] = {};
#pragma unroll
    for (int kc = 0; kc < 4; kc++) {
        f16x8 b[8];
#pragma unroll
        for (int nt = 0; nt < 8; nt++)
            b[nt] = *(const f16x8*)&Ws[(nt * 16 + lrow) * LDK + kc * 32 + quad * 8];
#pragma unroll
        for (int nt = 0; nt < 8; nt++) {
            acc[0][nt] = __builtin_amdgcn_mfma_f32_16x16x32_f16(a[0][kc], b[nt], acc[0][nt], 0, 0, 0);
            acc[1][nt] = __builtin_amdgcn_mfma_f32_16x16x32_f16(a[1][kc], b[nt], acc[1][nt], 0, 0, 0);
        }
    }
    __syncthreads();
#pragma unroll
    for (int mt = 0; mt < 2; mt++) {
#pragma unroll
        for (int r = 0; r < 4; r++) {
            int lr = wave * 32 + mt * 16 + quad * 4 + r;
            int grow = r0 + lr;
            float dv = (grow < nrows) ? dinv[grow] : 0.f;
#pragma unroll
            for (int nt = 0; nt < 8; nt++)
                Ws[lr * 132 + nt * 16 + lrow] = (f16)(acc[mt][nt][r] * dv);
        }
    }
    __syncthreads();
#pragma unroll
    for (int it = 0; it < 8; it++) {
        int c = it * 256 + tid;
        int rw = c >> 4;
        int col = (c & 15) * 8;
        int grow = r0 + rw;
        if (grow < nrows)
            *(f16x8*)&H[(size_t)grow * F + col] = *(const f16x8*)&Ws[rw * 132 + col];
    }
}

// ---------------- aggregation: quarter-wave 16B gathers, no per-edge dinv ----------------

__launch_bounds__(256)
__global__ void k_agg(const f16* __restrict__ H16, const int* __restrict__ row,
                      const unsigned int* __restrict__ edges,
                      const float* __restrict__ dinv, const float* __restrict__ bias,
                      f16* __restrict__ out, int n) {
    int node = blockIdx.x * 4 + (threadIdx.x >> 6);
    if (node >= n) return;
    int lane = threadIdx.x & 63;
    int qq = lane >> 4;
    int sub = lane & 15;
    float acc[8] = {0.f, 0.f, 0.f, 0.f, 0.f, 0.f, 0.f, 0.f};
    float acc2[8] = {0.f, 0.f, 0.f, 0.f, 0.f, 0.f, 0.f, 0.f};
    int beg = row[node], end = row[node + 1];
    int deg = end - beg;
    int t = qq;
    for (; t + 4 < deg; t += 8) {
        unsigned int e0 = edges[beg + t];
        unsigned int e1 = edges[beg + t + 4];
        float w0 = unpackw(e0);
        float w1 = unpackw(e1);
        f16x8 v0 = *(const f16x8*)&H16[(size_t)(e0 >> 15) * F + sub * 8];
        f16x8 v1 = *(const f16x8*)&H16[(size_t)(e1 >> 15) * F + sub * 8];
#pragma unroll
        for (int j = 0; j < 8; j++) {
            acc[j] = fmaf(w0, (float)v0[j], acc[j]);
            acc2[j] = fmaf(w1, (float)v1[j], acc2[j]);
        }
    }
    for (; t < deg; t += 4) {
        unsigned int e0 = edges[beg + t];
        float w0 = unpackw(e0);
        f16x8 v0 = *(const f16x8*)&H16[(size_t)(e0 >> 15) * F + sub * 8];
#pragma unroll
        for (int j = 0; j < 8; j++)
            acc[j] = fmaf(w0, (float)v0[j], acc[j]);
    }
#pragma unroll
    for (int j = 0; j < 8; j++) {
        acc[j] += acc2[j];
        acc[j] += __shfl_xor(acc[j], 16, 64);
        acc[j] += __shfl_xor(acc[j], 32, 64);
    }
    if (lane < 16) {
        float dd = dinv[node];
        f16x8 h = *(const f16x8*)&H16[(size_t)node * F + lane * 8];
        float4 b0 = *(const float4*)&bias[lane * 8];
        float4 b1 = *(const float4*)&bias[lane * 8 + 4];
        float bb[8] = {b0.x, b0.y, b0.z, b0.w, b1.x, b1.y, b1.z, b1.w};
        f16x8 o;
#pragma unroll
        for (int j = 0; j < 8; j++) {
            float r = fmaxf(fmaf(dd, acc[j] + (float)h[j], bb[j]), 0.f);
            o[j] = (f16)r;
        }
        *(f16x8*)&out[(size_t)node * F + lane * 8] = o;
    }
}

// agg3 fused with final dot: s'[node] = dinv[node] * ( relu(agg3) . Wfin )
__launch_bounds__(256)
__global__ void k_agg_dot(const f16* __restrict__ H16, const int* __restrict__ row,
                          const unsigned int* __restrict__ edges,
                          const float* __restrict__ dinv, const float* __restrict__ bias,
                          const float* __restrict__ Wf, float* __restrict__ sout, int n) {
    int node = blockIdx.x * 4 + (threadIdx.x >> 6);
    if (node >= n) return;
    int lane = threadIdx.x & 63;
    int qq = lane >> 4;
    int sub = lane & 15;
    float acc[8] = {0.f, 0.f, 0.f, 0.f, 0.f, 0.f, 0.f, 0.f};
    float acc2[8] = {0.f, 0.f, 0.f, 0.f, 0.f, 0.f, 0.f, 0.f};
    int beg = row[node], end = row[node + 1];
    int deg = end - beg;
    int t = qq;
    for (; t + 4 < deg; t += 8) {
        unsigned int e0 = edges[beg + t];
        unsigned int e1 = edges[beg + t + 4];
        float w0 = unpackw(e0);
        float w1 = unpackw(e1);
        f16x8 v0 = *(const f16x8*)&H16[(size_t)(e0 >> 15) * F + sub * 8];
        f16x8 v1 = *(const f16x8*)&H16[(size_t)(e1 >> 15) * F + sub * 8];
#pragma unroll
        for (int j = 0; j < 8; j++) {
            acc[j] = fmaf(w0, (float)v0[j], acc[j]);
            acc2[j] = fmaf(w1, (float)v1[j], acc2[j]);
        }
    }
    for (; t < deg; t += 4) {
        unsigned int e0 = edges[beg + t];
        float w0 = unpackw(e0);
        f16x8 v0 = *(const f16x8*)&H16[(size_t)(e0 >> 15) * F + sub * 8];
#pragma unroll
        for (int j = 0; j < 8; j++)
            acc[j] = fmaf(w0, (float)v0[j], acc[j]);
    }
#pragma unroll
    for (int j = 0; j < 8; j++) {
        acc[j] += acc2[j];
        acc[j] += __shfl_xor(acc[j], 16, 64);
        acc[j] += __shfl_xor(acc[j], 32, 64);
    }
    if (lane < 16) {
        float dd = dinv[node];
        f16x8 h = *(const f16x8*)&H16[(size_t)node * F + lane * 8];
        float4 b0 = *(const float4*)&bias[lane * 8];
        float4 b1 = *(const float4*)&bias[lane * 8 + 4];
        float bb[8] = {b0.x, b0.y, b0.z, b0.w, b1.x, b1.y, b1.z, b1.w};
        float4 w0 = *(const float4*)&Wf[lane * 8];
        float4 w1 = *(const float4*)&Wf[lane * 8 + 4];
        float ww[8] = {w0.x, w0.y, w0.z, w0.w, w1.x, w1.y, w1.z, w1.w};
        float p = 0.f;
#pragma unroll
        for (int j = 0; j < 8; j++)
            p += fmaxf(fmaf(dd, acc[j] + (float)h[j], bb[j]), 0.f) * ww[j];
        p += __shfl_xor(p, 8, 64);
        p += __shfl_xor(p, 4, 64);
        p += __shfl_xor(p, 2, 64);
        p += __shfl_xor(p, 1, 64);
        if (lane == 0) sout[node] = dd * p;
    }
}

__global__ void k_aggs(const float* __restrict__ s, const int* __restrict__ row,
                       const unsigned int* __restrict__ edges,
                       const float* __restrict__ dinv, const float* __restrict__ bf,
                       float* __restrict__ out, int n) {
    int i = blockIdx.x * blockDim.x + threadIdx.x;
    if (i >= n) return;
    float dd = dinv[i];
    float ae = s[i];
    int beg = row[i], end = row[i + 1];
    for (int j = beg; j < end; j++) {
        unsigned int p = edges[j];
        ae = fmaf(unpackw(p), s[p >> 15], ae);
    }
    out[i] = fmaf(dd, ae, bf[0]);
}

// ---------------- host launch ----------------

extern "C" void kernel_launch(void* const* d_in, const int* in_sizes, int n_in,
                              void* d_out, int out_size, void* d_ws, size_t ws_size,
                              hipStream_t stream) {
    const float* x    = (const float*)d_in[0];
    const int*   ei   = (const int*)d_in[1];
    const float* ew   = (const float*)d_in[2];
    const float* Win  = (const float*)d_in[3];
    const float* bin  = (const float*)d_in[4];
    const float* Wmid = (const float*)d_in[5];
    const float* bmid = (const float*)d_in[6];
    const float* Wfin = (const float*)d_in[7];
    const float* bfin = (const float*)d_in[8];
    float* out = (float*)d_out;

    char* ws = (char*)d_ws;
    size_t off = 0;
    auto alloc = [&](size_t bytes) -> char* {
        char* p = ws + off;
        off = (off + bytes + 255) & ~(size_t)255;
        return p;
    };
    float* dinv  = (float*)alloc((size_t)N_NODES * 4);
    int*   row   = (int*)alloc((size_t)(N_NODES + 1) * 4);
    unsigned int* edges = (unsigned int*)alloc((size_t)N_EDGES * 4);
    int*   bktcnt = (int*)alloc(256 * 4);
    int*   gbase  = (int*)alloc(256 * 4);
    int*   gcur   = (int*)alloc(256 * 4);
    f16*   wtin  = (f16*)alloc(128 * 128 * 2);
    f16*   wtmid = (f16*)alloc(128 * 128 * 2);
    f16*   H16   = (f16*)alloc((size_t)N_NODES * F * 2);   // gemm out (dinv-scaled) / agg in
    f16*   AB16  = (f16*)alloc((size_t)N_NODES * F * 2);   // x16 -> agg out chain
    // stage aliased into H16 (consumed by binB before gemm1 writes H16):
    int2* stage = (int2*)H16;                               // 12.8 MB
    float* sbuf = (float*)AB16;  // aliased: consumed by gemm3 before agg_dot writes

    dim3 b256(256);
    int gN = (N_NODES + 255) / 256;
    int gW = (N_NODES + 3) / 4;
    int gG = (N_NODES + 127) / 128;
    int n8 = N_NODES * F / 8;
    int gC = (n8 + 255) / 256;
    int gA = (N_EDGES + CHUNK - 1) / CHUNK;   // 391

    hipLaunchKernelGGL(k_zero0, dim3(1), b256, 0, stream, bktcnt);
    hipLaunchKernelGGL(k_bhist, dim3(gA), b256, 0, stream, ei, bktcnt, N_EDGES);
    hipLaunchKernelGGL(k_bktscan, dim3(1), b256, 0, stream, bktcnt, gbase, gcur, row);
    hipLaunchKernelGGL(k_binA, dim3(gA), b256, 0, stream, ei, ew, gcur, stage, N_EDGES);
    hipLaunchKernelGGL(k_binB, dim3(NCBK), b256, 0, stream, stage, gbase, edges, row, dinv);
    hipLaunchKernelGGL(k_cvt, dim3(gC), b256, 0, stream, x, AB16, n8);
    hipLaunchKernelGGL(k_wt2, dim3(2), b256, 0, stream, Win, Wmid, wtin, wtmid);

    hipLaunchKernelGGL(k_gemm16, dim3(gG), b256, 0, stream, AB16, wtin, dinv, H16, N_NODES);
    hipLaunchKernelGGL(k_agg, dim3(gW), b256, 0, stream, H16, row, edges, dinv, bin, AB16, N_NODES);
    hipLaunchKernelGGL(k_gemm16, dim3(gG), b256, 0, stream, AB16, wtmid, dinv, H16, N_NODES);
    hipLaunchKernelGGL(k_agg, dim3(gW), b256, 0, stream, H16, row, edges, dinv, bmid, AB16, N_NODES);
    hipLaunchKernelGGL(k_gemm16, dim3(gG), b256, 0, stream, AB16, wtmid, dinv, H16, N_NODES);
    hipLaunchKernelGGL(k_agg_dot, dim3(gW), b256, 0, stream, H16, row, edges, dinv, bmid, Wfin, sbuf, N_NODES);
    hipLaunchKernelGGL(k_aggs, dim3(gN), b256, 0, stream, sbuf, row, edges, dinv, bfin, out, N_NODES);
}